// Round 15
// baseline (32.051 us; speedup 1.0000x reference)
//
#include <hip/hip_runtime.h>

// Cone-beam projection: D=W=H=128 volume, 180x180 detector, BATCH=4.
// out[b][0][i][j] = dx(b,i,j) * sum_{k=0..127} trilinear(vol, ray(b,i,j,k))
//
// Index-space ray, linear in k:
//   iz(k) = izb + k*izs  (D axis, stride 2^14)
//   iy(k) = k*(127/128)  (W axis, never OOB)
//   ix(k) = ixb + k*ixs  (H axis, stride 1)
//
// SHAPE: R4-proven: 256-thr blocks = 32 adjacent-j px x 8 k-chunks of 16;
// 4050 blocks (~2x residency); coprime swizzle for CU balance.
//
// ROUND-15 (= R14 intent, compile fix: macro var renamed mk): 3-phase split
// per thread within its 16-k chunk:
//   [kai,l0) masked | [l0,l1) LEAN | [l1,kbi) masked
// where lean = { k : ix,iz in [0,127) } -> x0,z0 in [0,126]: NO masks, NO
// clamps, NO weight swaps (~35 VALU vs ~55). Lean bounds are EXACT roots
// with endpoint verification (evaluate ix/iz at l0 and l1-1; shrink on
// 1-ulp rounding leak; linear+monotone => interior then provably in-range),
// and are clamped inside [kai,kbi) so total trips never exceed round-13's.
// Interior waves (most of the work; 32 adjacent j share the footprint) run
// lean wave-uniformly; only footprint-boundary waves diverge 1-3 trips.
// Unlike R5: no conservative margin, no 512-thr coupling, no trip growth.
//
// Negative results (do not revisit): per-lane margin-split @512thr (R5);
// 64px waves (R5/R7); pad staging (R8: L2 dirty per replay); XCD k-split +
// reduce (R9); unroll-4 short trips (R10); branch-free dual-stream (R12);
// single-wave blocks (R13: neutral).

#define RES 180
#define NPIX (4 * RES * RES)       // 129600
#define PPB 32
#define NCHUNK (NPIX / PPB)        // 4050
#define CHUNK_STRIDE 1013          // prime, coprime to 4050

typedef struct __attribute__((packed, aligned(4))) { float x, y; } f2u;

__global__ __launch_bounds__(256) void proj_kernel(
    const float* __restrict__ vol, const float* __restrict__ poses,
    const float* __restrict__ spacing, float* __restrict__ out) {
  const int tid = threadIdx.x;
  const int lp  = tid & 31;       // pixel slot
  const int ks  = tid >> 5;       // k-chunk 0..7 (16 k each)
  const int chunk = (int)(((long long)blockIdx.x * CHUNK_STRIDE) % NCHUNK);
  const int gpix = chunk * PPB + lp;

  const int b   = gpix / (RES * RES);
  const int rem = gpix - b * (RES * RES);
  const int i   = rem / RES;
  const int j   = rem - i * RES;

  const float ex = poses[b * 3 + 0];
  const float ey = poses[b * 3 + 1];
  const float ez = poses[b * 3 + 2];

  const float Ix = ((float)i - 90.0f) - ex;
  const float Iy = -ey;                // ~ +300
  const float Iz = ((float)j - 90.0f) - ez;

  const float c     = 63.5f / 64.0f;   // exact in fp32
  const float invIy = 1.0f / Iy;

  const float izb = fmaf(ex + Ix, c, 63.5f);
  const float izs = Ix * invIy * c;
  const float ixb = fmaf(ez + Iz, c, 63.5f);
  const float ixs = Iz * invIy * c;

  // ---- valid k-interval (masked-correct): ix,iz in (-1,128) ----
  const int k0 = ks * 16;
  float ka = (float)k0, kb = (float)(k0 + 16);
  if (ixs > 1e-12f)       { ka = fmaxf(ka, (-1.0f - ixb) / ixs); kb = fminf(kb, (128.0f - ixb) / ixs); }
  else if (ixs < -1e-12f) { ka = fmaxf(ka, (128.0f - ixb) / ixs); kb = fminf(kb, (-1.0f - ixb) / ixs); }
  else if (ixb <= -1.0f || ixb >= 128.0f) { kb = ka; }
  if (izs > 1e-12f)       { ka = fmaxf(ka, (-1.0f - izb) / izs); kb = fminf(kb, (128.0f - izb) / izs); }
  else if (izs < -1e-12f) { ka = fmaxf(ka, (128.0f - izb) / izs); kb = fminf(kb, (-1.0f - izb) / izs); }
  else if (izb <= -1.0f || izb >= 128.0f) { kb = ka; }
  ka = fmaxf(ka, (float)k0);
  kb = fminf(kb, (float)(k0 + 16));
  const int kai = (int)ceilf(ka);
  const int kbi = (int)ceilf(kb);

  // ---- lean sub-interval: ix,iz in [0,127) -> x0,z0 in [0,126] ----
  float la = ka, lb = kb;
  if (ixs > 1e-12f)       { la = fmaxf(la, (0.0f - ixb) / ixs); lb = fminf(lb, (127.0f - ixb) / ixs); }
  else if (ixs < -1e-12f) { la = fmaxf(la, (127.0f - ixb) / ixs); lb = fminf(lb, (0.0f - ixb) / ixs); }
  else if (ixb < 0.0f || ixb >= 127.0f) { lb = la; }
  if (izs > 1e-12f)       { la = fmaxf(la, (0.0f - izb) / izs); lb = fminf(lb, (127.0f - izb) / izs); }
  else if (izs < -1e-12f) { la = fmaxf(la, (127.0f - izb) / izs); lb = fminf(lb, (0.0f - izb) / izs); }
  else if (izb < 0.0f || izb >= 127.0f) { lb = la; }
  int l0 = (int)ceilf(la);
  int l1 = (int)ceilf(lb);
  l0 = min(max(l0, kai), kbi);
  l1 = min(max(l1, l0), kbi);
  // endpoint verification vs 1-ulp root rounding (linearity => interior safe)
  if (l1 > l0) {
    const float x_ = fmaf((float)l0, ixs, ixb), z_ = fmaf((float)l0, izs, izb);
    if (!(x_ >= 0.0f && x_ < 127.0f && z_ >= 0.0f && z_ < 127.0f)) ++l0;
  }
  if (l1 > l0) {
    const float x_ = fmaf((float)(l1 - 1), ixs, ixb), z_ = fmaf((float)(l1 - 1), izs, izb);
    if (!(x_ >= 0.0f && x_ < 127.0f && z_ >= 0.0f && z_ < 127.0f)) --l1;
  }
  if (l1 < l0) l1 = l0;

  float sum = 0.0f;

#define MASKED_BODY(kk)                                                        \
  {                                                                            \
    const int mk = (kk);                                                       \
    const float kf = (float)mk;                                                \
    const float ix = fmaf(kf, ixs, ixb);                                       \
    const float iy = kf * c;                                                   \
    const float iz = fmaf(kf, izs, izb);                                       \
    const float fx = floorf(ix), fy = floorf(iy), fz = floorf(iz);             \
    const int x0 = (int)fx, y0 = (int)fy, z0 = (int)fz;                        \
    const float wx1 = ix - fx, wy1 = iy - fy, wz1 = iz - fz;                   \
    const float wx0 = 1.0f - wx1, wy0 = 1.0f - wy1, wz0 = 1.0f - wz1;          \
    const float vx0 = ((unsigned)x0       < 128u) ? wx0 : 0.0f;                \
    const float vx1 = ((unsigned)(x0 + 1) < 128u) ? wx1 : 0.0f;                \
    const float vz0 = ((unsigned)z0       < 128u) ? wz0 : 0.0f;                \
    const float vz1 = ((unsigned)(z0 + 1) < 128u) ? wz1 : 0.0f;                \
    const int xb2 = min(max(x0, 0), 126);                                      \
    const bool inx = (x0 == xb2);                                              \
    const float wlo = inx ? vx0 : vx1;                                         \
    const float whi = inx ? vx1 : vx0;                                         \
    const int zc0 = min(max(z0, 0), 127), zc1 = min(max(z0 + 1, 0), 127);      \
    const float* base = vol + ((zc0 << 14) + (y0 << 7) + xb2);                 \
    const int dz = (zc1 - zc0) << 14;                                          \
    const f2u v00 = *(const f2u*)(base);                                       \
    const f2u v01 = *(const f2u*)(base + 128);                                 \
    const f2u v10 = *(const f2u*)(base + dz);                                  \
    const f2u v11 = *(const f2u*)(base + dz + 128);                            \
    const float s00 = fmaf(whi, v00.y, wlo * v00.x);                           \
    const float s01 = fmaf(whi, v01.y, wlo * v01.x);                           \
    const float s10 = fmaf(whi, v10.y, wlo * v10.x);                           \
    const float s11 = fmaf(whi, v11.y, wlo * v11.x);                           \
    const float s0  = fmaf(wy1, s01, wy0 * s00);                               \
    const float s1  = fmaf(wy1, s11, wy0 * s10);                               \
    sum = fmaf(vz0, s0, sum);                                                  \
    sum = fmaf(vz1, s1, sum);                                                  \
  }

  for (int k = kai; k < l0; ++k) MASKED_BODY(k)

#pragma unroll 2
  for (int k = l0; k < l1; ++k) {
    // lean: x0,z0 in [0,126] proven; weights unmasked == masks all 1;
    // arithmetic bit-identical to MASKED_BODY for these samples.
    const float kf = (float)k;
    const float ix = fmaf(kf, ixs, ixb);
    const float iy = kf * c;
    const float iz = fmaf(kf, izs, izb);
    const float fx = floorf(ix), fy = floorf(iy), fz = floorf(iz);
    const int x0 = (int)fx, y0 = (int)fy, z0 = (int)fz;
    const float wx1 = ix - fx, wy1 = iy - fy, wz1 = iz - fz;
    const float wx0 = 1.0f - wx1, wy0 = 1.0f - wy1, wz0 = 1.0f - wz1;

    const float* base = vol + ((z0 << 14) + (y0 << 7) + x0);
    const f2u v00 = *(const f2u*)(base);
    const f2u v01 = *(const f2u*)(base + 128);
    const f2u v10 = *(const f2u*)(base + 16384);
    const f2u v11 = *(const f2u*)(base + 16384 + 128);

    const float s00 = fmaf(wx1, v00.y, wx0 * v00.x);
    const float s01 = fmaf(wx1, v01.y, wx0 * v01.x);
    const float s10 = fmaf(wx1, v10.y, wx0 * v10.x);
    const float s11 = fmaf(wx1, v11.y, wx0 * v11.x);
    const float s0  = fmaf(wy1, s01, wy0 * s00);
    const float s1  = fmaf(wy1, s11, wy0 * s10);
    sum = fmaf(wz0, s0, sum);
    sum = fmaf(wz1, s1, sum);
  }

  for (int k = l1; k < kbi; ++k) MASKED_BODY(k)
#undef MASKED_BODY

  __shared__ float part[256];
  part[tid] = sum;
  __syncthreads();

  if (tid < PPB) {
    float tot = 0.0f;
#pragma unroll
    for (int s = 0; s < 8; ++s) tot += part[tid + 32 * s];
    const float ax = Ix * invIy * spacing[0];
    const float az = Iz * invIy * spacing[2];
    const float sy = spacing[1];
    out[gpix] = tot * sqrtf(fmaf(ax, ax, fmaf(az, az, sy * sy)));
  }
}

extern "C" void kernel_launch(void* const* d_in, const int* in_sizes, int n_in,
                              void* d_out, int out_size, void* d_ws, size_t ws_size,
                              hipStream_t stream) {
  const float* vol     = (const float*)d_in[0];   // [1,1,128,128,128] fp32
  const float* poses   = (const float*)d_in[1];   // [4,3] fp32
  const float* spacing = (const float*)d_in[2];   // [3] fp32
  float* out = (float*)d_out;                     // [4,1,180,180] fp32

  proj_kernel<<<NCHUNK, 256, 0, stream>>>(vol, poses, spacing, out);
}

// Round 16
// 25.835 us; speedup vs baseline: 1.2406x; 1.2406x over previous
//
#include <hip/hip_runtime.h>

// Cone-beam projection: D=W=H=128 volume, 180x180 detector, BATCH=4.
// out[b][0][i][j] = dx(b,i,j) * sum_{k=0..127} trilinear(vol, ray(b,i,j,k))
//
// FINAL (champion = round-11, 25.9us): index-space ray linear in k; each
// thread owns TWO MIRRORED 8-k chunks (c, 15-c) as divergent-if dual
// streams; per-thread loop covers only valid k (ix,iz in (-1,128));
// per-axis masked weights reproduce grid_sample zero padding exactly.
// 256-thr blocks = 32 adjacent-j px x 8 k-threads; 4050 blocks; coprime
// swizzle for CU load balance.
//
// Exhausted-lever ledger (falsified, do not revisit):
//   TLP scaling        R4/R9/R13  (saturated; occupancy-neutral)
//   per-wave MLP       R10/R12    (unroll remainder-dominated; predication
//                                  costs > overlap gains)
//   locality partition R9         (vol is L3-resident; split tax > win)
//   staging            R8         (per-replay L2 dirty + flush)
//   block granularity  R13        (single-wave blocks neutral)
//   VALU-lean bodies   R5/R7/R15  (bounds setup + seam divergence > savings)
// Counter state at champion: HBM ~6% peak, VALU ~55-60%, no pipe saturated
// -> VALU-issue x gather-latency composite floor for this algorithm.

#define RES 180
#define NPIX (4 * RES * RES)       // 129600
#define PPB 32
#define NCHUNK (NPIX / PPB)        // 4050
#define CHUNK_STRIDE 1013          // prime, coprime to 4050

typedef struct __attribute__((packed, aligned(4))) { float x, y; } f2u;

__global__ __launch_bounds__(256) void proj_kernel(
    const float* __restrict__ vol, const float* __restrict__ poses,
    const float* __restrict__ spacing, float* __restrict__ out) {
  const int tid = threadIdx.x;
  const int lp  = tid & 31;       // pixel slot
  const int ks  = tid >> 5;       // k-thread 0..7
  const int chunk = (int)(((long long)blockIdx.x * CHUNK_STRIDE) % NCHUNK);
  const int gpix = chunk * PPB + lp;

  const int b   = gpix / (RES * RES);
  const int rem = gpix - b * (RES * RES);
  const int i   = rem / RES;
  const int j   = rem - i * RES;

  const float ex = poses[b * 3 + 0];
  const float ey = poses[b * 3 + 1];
  const float ez = poses[b * 3 + 2];

  const float Ix = ((float)i - 90.0f) - ex;
  const float Iy = -ey;                // ~ +300
  const float Iz = ((float)j - 90.0f) - ez;

  const float c     = 63.5f / 64.0f;   // exact in fp32
  const float invIy = 1.0f / Iy;

  const float izb = fmaf(ex + Ix, c, 63.5f);
  const float izs = Ix * invIy * c;
  const float ixb = fmaf(ez + Iz, c, 63.5f);
  const float ixs = Iz * invIy * c;

  // ---- global valid k-interval: ix,iz in (-1,128), k in [0,128) ----
  float ka = 0.0f, kb = 128.0f;
  if (ixs > 1e-12f)       { ka = fmaxf(ka, (-1.0f - ixb) / ixs); kb = fminf(kb, (128.0f - ixb) / ixs); }
  else if (ixs < -1e-12f) { ka = fmaxf(ka, (128.0f - ixb) / ixs); kb = fminf(kb, (-1.0f - ixb) / ixs); }
  else if (ixb <= -1.0f || ixb >= 128.0f) { kb = ka; }
  if (izs > 1e-12f)       { ka = fmaxf(ka, (-1.0f - izb) / izs); kb = fminf(kb, (128.0f - izb) / izs); }
  else if (izs < -1e-12f) { ka = fmaxf(ka, (128.0f - izb) / izs); kb = fminf(kb, (-1.0f - izb) / izs); }
  else if (izb <= -1.0f || izb >= 128.0f) { kb = ka; }
  ka = fmaxf(ka, 0.0f);
  kb = fminf(kb, 128.0f);
  const int kai = (int)ceilf(ka);
  const int kbi = (int)ceilf(kb);   // masks keep edges exact

  // ---- two mirrored 8-k chunks per thread (correlated lengths) ----
  const int c1 = ks;              // k in [8c1, 8c1+8)
  const int c2 = 15 - ks;         // k in [8c2, 8c2+8)
  const int a1 = max(kai, 8 * c1), b1 = min(kbi, 8 * c1 + 8);
  const int a2 = max(kai, 8 * c2), b2 = min(kbi, 8 * c2 + 8);
  const int n1 = max(0, b1 - a1);
  const int n2 = max(0, b2 - a2);
  const int nt = max(n1, n2);

  float sum = 0.0f;

#define BODY(kk)                                                               \
  {                                                                            \
    const int mk = (kk);                                                       \
    const float kf = (float)mk;                                                \
    const float ix = fmaf(kf, ixs, ixb);                                       \
    const float iy = kf * c;                                                   \
    const float iz = fmaf(kf, izs, izb);                                       \
    const float fx = floorf(ix), fy = floorf(iy), fz = floorf(iz);             \
    const int x0 = (int)fx, y0 = (int)fy, z0 = (int)fz;                        \
    const float wx1 = ix - fx, wy1 = iy - fy, wz1 = iz - fz;                   \
    const float wx0 = 1.0f - wx1, wy0 = 1.0f - wy1, wz0 = 1.0f - wz1;          \
    const float vx0 = ((unsigned)x0       < 128u) ? wx0 : 0.0f;                \
    const float vx1 = ((unsigned)(x0 + 1) < 128u) ? wx1 : 0.0f;                \
    const float vz0 = ((unsigned)z0       < 128u) ? wz0 : 0.0f;                \
    const float vz1 = ((unsigned)(z0 + 1) < 128u) ? wz1 : 0.0f;                \
    const int xb2 = min(max(x0, 0), 126);                                      \
    const bool inx = (x0 == xb2);                                              \
    const float wlo = inx ? vx0 : vx1;                                         \
    const float whi = inx ? vx1 : vx0;                                         \
    const int zc0 = min(max(z0, 0), 127), zc1 = min(max(z0 + 1, 0), 127);      \
    const float* base = vol + ((zc0 << 14) + (y0 << 7) + xb2);                 \
    const int dz = (zc1 - zc0) << 14;                                          \
    const f2u v00 = *(const f2u*)(base);                                       \
    const f2u v01 = *(const f2u*)(base + 128);                                 \
    const f2u v10 = *(const f2u*)(base + dz);                                  \
    const f2u v11 = *(const f2u*)(base + dz + 128);                            \
    const float s00 = fmaf(whi, v00.y, wlo * v00.x);                           \
    const float s01 = fmaf(whi, v01.y, wlo * v01.x);                           \
    const float s10 = fmaf(whi, v10.y, wlo * v10.x);                           \
    const float s11 = fmaf(whi, v11.y, wlo * v11.x);                           \
    const float s0  = fmaf(wy1, s01, wy0 * s00);                               \
    const float s1  = fmaf(wy1, s11, wy0 * s10);                               \
    sum = fmaf(vz0, s0, sum);                                                  \
    sum = fmaf(vz1, s1, sum);                                                  \
  }

  for (int t = 0; t < nt; ++t) {
    if (t < n1) BODY(a1 + t)
    if (t < n2) BODY(a2 + t)
  }
#undef BODY

  __shared__ float part[256];
  part[tid] = sum;
  __syncthreads();

  if (tid < PPB) {
    float tot = 0.0f;
#pragma unroll
    for (int s = 0; s < 8; ++s) tot += part[tid + 32 * s];
    const float ax = Ix * invIy * spacing[0];
    const float az = Iz * invIy * spacing[2];
    const float sy = spacing[1];
    out[gpix] = tot * sqrtf(fmaf(ax, ax, fmaf(az, az, sy * sy)));
  }
}

extern "C" void kernel_launch(void* const* d_in, const int* in_sizes, int n_in,
                              void* d_out, int out_size, void* d_ws, size_t ws_size,
                              hipStream_t stream) {
  const float* vol     = (const float*)d_in[0];   // [1,1,128,128,128] fp32
  const float* poses   = (const float*)d_in[1];   // [4,3] fp32
  const float* spacing = (const float*)d_in[2];   // [3] fp32
  float* out = (float*)d_out;                     // [4,1,180,180] fp32

  proj_kernel<<<NCHUNK, 256, 0, stream>>>(vol, poses, spacing, out);
}